// Round 2
// baseline (358.500 us; speedup 1.0000x reference)
//
#include <hip/hip_runtime.h>
#include <math.h>

// Problem constants
#define BATCH 8
#define NNODE 512
#define BN 4096           // BATCH*NNODE
#define DIM 128
#define HID 64
#define CAP 64            // max neighbors per row (mean ~20, 10 sigma margin)

__device__ __forceinline__ float sigmoidf(float x) {
  return 1.f / (1.f + expf(-x));
}
__device__ __forceinline__ float wave_sum(float v) {
  for (int off = 1; off < 64; off <<= 1) v += __shfl_xor(v, off, 64);
  return v;
}

// ---------------------------------------------------------------------------
// K1: per-node MLPs: kappa + f0..f2.  16 nodes/block, 4 nodes/wave so each
// W1[k][lane] LDS read feeds 4 FMAs.  Last block computes c1 = wm_mlp(1.0)
// (weights = weight_mlp(A)*A == c1*A since A is exactly {0,1}).
// ---------------------------------------------------------------------------
__global__ __launch_bounds__(256) void k_node_mlps(
    const float* X, const float* cW1, const float* cb1, const float* cW2,
    const float* cb2, const float* fW1, const float* fb1, const float* fW2,
    const float* fb2, const float* wm_W1, const float* wm_b1,
    const float* wm_W2, const float* wm_b2, const float* wm_W3,
    const float* wm_b3, float* kap, float* f, float* c1_out) {
  if (blockIdx.x == BN / 16) {  // special block: scalar weight-MLP(1.0)
    __shared__ float u[64];
    __shared__ float y[32];
    int l = threadIdx.x;
    if (l < 64) u[l] = fmaxf(0.f, wm_W1[l] + wm_b1[l]);
    __syncthreads();
    if (l < 32) {
      float a = wm_b2[l];
      for (int k = 0; k < 64; k++) a += u[k] * wm_W2[k * 32 + l];
      y[l] = fmaxf(0.f, a);
    }
    __syncthreads();
    if (l == 0) {
      float a = wm_b3[0];
      for (int k = 0; k < 32; k++) a += y[k] * wm_W3[k];
      *c1_out = sigmoidf(a);
    }
    return;
  }
  __shared__ float W1s[DIM * HID];  // 32KB
  __shared__ float xs[16][DIM];     // 8KB
  int tid = threadIdx.x, wave = tid >> 6, lane = tid & 63;
  int node0 = blockIdx.x * 16;
  for (int t = tid; t < 16 * DIM; t += 256)
    ((float*)xs)[t] = X[(size_t)node0 * DIM + t];
  const float* x0 = xs[wave * 4 + 0];
  const float* x1 = xs[wave * 4 + 1];
  const float* x2 = xs[wave * 4 + 2];
  const float* x3 = xs[wave * 4 + 3];
  for (int m = 0; m < 4; m++) {
    const float* W1 = (m == 0) ? cW1 : fW1 + (size_t)(m - 1) * DIM * HID;
    __syncthreads();
    for (int t = tid; t < DIM * HID; t += 256) W1s[t] = W1[t];
    __syncthreads();
    const float* b1 = (m == 0) ? cb1 : fb1 + (m - 1) * HID;
    const float* W2 = (m == 0) ? cW2 : fW2 + (m - 1) * HID;
    float b2v = (m == 0) ? cb2[0] : fb2[m - 1];
    float w2l = W2[lane];
    float bb = b1[lane];
    float acc0 = bb, acc1 = bb, acc2 = bb, acc3 = bb;
    for (int k = 0; k < DIM; k += 4) {
      float w0 = W1s[(k + 0) * HID + lane];
      float w1 = W1s[(k + 1) * HID + lane];
      float w2 = W1s[(k + 2) * HID + lane];
      float w3 = W1s[(k + 3) * HID + lane];
      float4 a;
      a = *(const float4*)&x0[k];
      acc0 += a.x * w0 + a.y * w1 + a.z * w2 + a.w * w3;
      a = *(const float4*)&x1[k];
      acc1 += a.x * w0 + a.y * w1 + a.z * w2 + a.w * w3;
      a = *(const float4*)&x2[k];
      acc2 += a.x * w0 + a.y * w1 + a.z * w2 + a.w * w3;
      a = *(const float4*)&x3[k];
      acc3 += a.x * w0 + a.y * w1 + a.z * w2 + a.w * w3;
    }
    float s0 = wave_sum(fmaxf(0.f, acc0) * w2l);
    float s1 = wave_sum(fmaxf(0.f, acc1) * w2l);
    float s2 = wave_sum(fmaxf(0.f, acc2) * w2l);
    float s3 = wave_sum(fmaxf(0.f, acc3) * w2l);
    if (lane < 4) {
      float sv = (lane == 0) ? s0 : (lane == 1) ? s1 : (lane == 2) ? s2 : s3;
      float s = sigmoidf(sv + b2v);
      int node = node0 + wave * 4 + lane;
      if (m == 0) kap[node] = s;
      else f[node * 3 + (m - 1)] = s;
    }
  }
}

// ---------------------------------------------------------------------------
// K2: fused CSR build (blocks [0,1024): 4 rows/block, wave/row) + top-k rank
// masks (blocks [1024,1032): one batch each) + loss_acc zero.
// ---------------------------------------------------------------------------
__global__ __launch_bounds__(256) void k_csr_masks(
    const float* A, const float* kap, const int* p_ptr, int* csr, int* cnt_arr,
    float* deg, float* M1, float* M2, float* loss_acc) {
  int bid = blockIdx.x;
  if (bid < BN / 4) {
    int wave = threadIdx.x >> 6, lane = threadIdx.x & 63;
    int r = bid * 4 + wave;
    const float* row = A + (size_t)r * NNODE;
    int base = r * CAP, cnt = 0;
    for (int c = 0; c < NNODE / 64; c++) {
      int j = c * 64 + lane;
      bool nz = (row[j] != 0.f);
      unsigned long long mb = __ballot(nz);
      if (nz) {
        int pos = __popcll(mb & ((1ull << lane) - 1ull));
        int slot = cnt + pos;
        if (slot < CAP) csr[base + slot] = j;
      }
      cnt += (int)__popcll(mb);
    }
    if (lane == 0) {
      cnt_arr[r] = cnt < CAP ? cnt : CAP;
      deg[r] = (float)cnt;
    }
    return;
  }
  int b = bid - BN / 4;
  if (threadIdx.x == 0 && b == 0) *loss_acc = 0.f;
  __shared__ float ks[NNODE];
  for (int t = threadIdx.x; t < NNODE; t += 256) ks[t] = kap[b * NNODE + t];
  __syncthreads();
  int p = *p_ptr;
  int num1 = (NNODE * p) / 100;
  int num2 = (NNODE * 2 * p) / 100;
  int numm = num1 > num2 ? num1 : num2;
  for (int i = threadIdx.x; i < NNODE; i += 256) {
    float v = ks[i];
    int rank = 0;
    for (int j = 0; j < NNODE; j++) {
      float u = ks[j];
      rank += (u > v) || (u == v && j < i);  // jax.lax.top_k tie-break
    }
    M1[b * NNODE + i] = (rank < num1) ? 0.f : 1.f;
    M2[b * NNODE + i] = (rank < numm) ? 0.f : 1.f;
  }
}

// ---------------------------------------------------------------------------
// K3: curvature pass1 gather + elementwise gamma/df terms (w = c1*A).
// GG[r*12]: [gamma_i, df_i, fi*df_i] for i=0..2, then s1_i (i=0..2).
// ---------------------------------------------------------------------------
__global__ __launch_bounds__(256) void k_pass1_gamma(
    const float* f, const int* csr, const int* cnt, const float* deg,
    const float* c1p, float* GG) {
  int r = blockIdx.x * 256 + threadIdx.x;
  if (r >= BN) return;
  int b = r >> 9;
  const int* nb = csr + r * CAP;
  int n = cnt[r];
  float s1[3] = {0, 0, 0}, s2[3] = {0, 0, 0};
  int base = (b << 9) * 3;
  for (int t = 0; t < n; t++) {
    int j = nb[t];
    const float* fj = f + base + j * 3;
    float f0 = fj[0], f1 = fj[1], f2 = fj[2];
    s1[0] += f0; s1[1] += f1; s1[2] += f2;
    s2[0] += f0 * f0; s2[1] += f1 * f1; s2[2] += f2 * f2;
  }
  float c1 = *c1p, dA = deg[r];
  float* o = GG + (size_t)r * 12;
  for (int i = 0; i < 3; i++) {
    float fi = f[r * 3 + i];
    float gamma = 0.5f * c1 * (fi * fi * dA - 2.f * fi * s1[i] + s2[i]);
    float df = c1 * (fi * dA - s1[i]);
    o[i * 3 + 0] = gamma;
    o[i * 3 + 1] = df;
    o[i * 3 + 2] = fi * df;
    o[9 + i] = s1[i];
  }
}

// ---------------------------------------------------------------------------
// K4: curvature pass2 gather (float4 x3 per neighbor row) + loss reduction.
// ---------------------------------------------------------------------------
__global__ __launch_bounds__(256) void k_pass2(
    const float* f, const float* kap, const float* deg, const float* GG,
    const int* csr, const int* cnt, const float* c1p, float* loss_acc) {
  int r = blockIdx.x * 256 + threadIdx.x;
  float local = 0.f;
  if (r < BN) {
    int b = r >> 9;
    const int* nb = csr + r * CAP;
    int n = cnt[r];
    float T[9];
    for (int c = 0; c < 9; c++) T[c] = 0.f;
    size_t gbase = (size_t)(b << 9) * 12;
    for (int t = 0; t < n; t++) {
      int j = nb[t];
      const float4* g = (const float4*)(GG + gbase + (size_t)j * 12);
      float4 g0 = g[0], g1 = g[1], g2 = g[2];
      T[0] += g0.x; T[1] += g0.y; T[2] += g0.z;
      T[3] += g0.w; T[4] += g1.x; T[5] += g1.y;
      T[6] += g1.z; T[7] += g1.w; T[8] += g2.x;
    }
    float c1 = *c1p, dA = deg[r], kp = kap[r];
    const float* o = GG + (size_t)r * 12;
    for (int i = 0; i < 3; i++) {
      float fi = f[r * 3 + i];
      float s1 = o[9 + i];
      float gamma = o[i * 3 + 0], df = o[i * 3 + 1];
      float Tg = T[i * 3 + 0], Tdf = T[i * 3 + 1], Tfdf = T[i * 3 + 2];
      float dgamma = c1 * (gamma * dA - Tg);
      float gfd = 0.5f * c1 * (fi * df * dA - fi * Tdf - df * s1 + Tfdf);
      float gamma2 = 0.5f * dgamma - gfd;
      local += fmaxf(0.f, kp * gamma - gamma2);
    }
    local -= 3.f * kp;  // "- kappa.sum()" once per f_i
  }
  local = wave_sum(local);
  if ((threadIdx.x & 63) == 0) atomicAdd(loss_acc, local);
}

// ---------------------------------------------------------------------------
// GIN layer: agg = (1+eps)*h + M[i]*sum_{j in nbr, M[j]} h[j];
// h' = relu(relu(agg@W1+b1)@W2+b2).  16 nodes/block, 4 nodes/wave: each
// weight LDS read feeds 4 FMAs.  One __syncthreads (weight staging); agg/z
// LDS rows are wave-local so need no barrier.
// ---------------------------------------------------------------------------
template <int CIN>
__global__ __launch_bounds__(256) void k_gin(
    const float* hin, const float* W1, const float* b1, const float* W2,
    const float* b2, const float* eps_arr, int eps_idx, const int* csr,
    const int* cnt, const float* mask, float* hout) {
  __shared__ float W1s[CIN * HID];
  __shared__ float W2s[HID * HID];
  __shared__ float aggs[16][CIN];
  __shared__ float zs[16][HID];
  int tid = threadIdx.x, wave = tid >> 6, lane = tid & 63;
  int node0 = blockIdx.x * 16;
  for (int t = tid; t < CIN * HID; t += 256) W1s[t] = W1[t];
  for (int t = tid; t < HID * HID; t += 256) W2s[t] = W2[t];
  float eps1 = 1.f + eps_arr[eps_idx];
  for (int i = 0; i < 4; i++) {
    int ln = wave * 4 + i;
    int r = node0 + ln;
    int b = r >> 9;
    const float* hi = hin + (size_t)r * CIN;
    float a0 = eps1 * hi[lane];
    float a1 = (CIN == 128) ? eps1 * hi[lane + 64] : 0.f;
    bool rowon = (mask == nullptr) || (mask[r] != 0.f);
    if (rowon) {
      int n = cnt[r];
      const int* nb = csr + r * CAP;
      int nbase = (b << 9);
      for (int t = 0; t < n; t++) {
        int j = nb[t];
        int rj = nbase + j;
        if (mask && mask[rj] == 0.f) continue;
        const float* hj = hin + (size_t)rj * CIN;
        a0 += hj[lane];
        if (CIN == 128) a1 += hj[lane + 64];
      }
    }
    aggs[ln][lane] = a0;
    if (CIN == 128) aggs[ln][lane + 64] = a1;
  }
  __syncthreads();
  const float* x0 = aggs[wave * 4 + 0];
  const float* x1 = aggs[wave * 4 + 1];
  const float* x2 = aggs[wave * 4 + 2];
  const float* x3 = aggs[wave * 4 + 3];
  float bb = b1[lane];
  float acc0 = bb, acc1 = bb, acc2 = bb, acc3 = bb;
  for (int k = 0; k < CIN; k += 4) {
    float w0 = W1s[(k + 0) * HID + lane];
    float w1 = W1s[(k + 1) * HID + lane];
    float w2 = W1s[(k + 2) * HID + lane];
    float w3 = W1s[(k + 3) * HID + lane];
    float4 a;
    a = *(const float4*)&x0[k];
    acc0 += a.x * w0 + a.y * w1 + a.z * w2 + a.w * w3;
    a = *(const float4*)&x1[k];
    acc1 += a.x * w0 + a.y * w1 + a.z * w2 + a.w * w3;
    a = *(const float4*)&x2[k];
    acc2 += a.x * w0 + a.y * w1 + a.z * w2 + a.w * w3;
    a = *(const float4*)&x3[k];
    acc3 += a.x * w0 + a.y * w1 + a.z * w2 + a.w * w3;
  }
  zs[wave * 4 + 0][lane] = fmaxf(0.f, acc0);
  zs[wave * 4 + 1][lane] = fmaxf(0.f, acc1);
  zs[wave * 4 + 2][lane] = fmaxf(0.f, acc2);
  zs[wave * 4 + 3][lane] = fmaxf(0.f, acc3);
  const float* z0 = zs[wave * 4 + 0];
  const float* z1 = zs[wave * 4 + 1];
  const float* z2 = zs[wave * 4 + 2];
  const float* z3 = zs[wave * 4 + 3];
  float b2b = b2[lane];
  float c0 = b2b, c1 = b2b, c2 = b2b, c3 = b2b;
  for (int k = 0; k < HID; k += 4) {
    float w0 = W2s[(k + 0) * HID + lane];
    float w1 = W2s[(k + 1) * HID + lane];
    float w2 = W2s[(k + 2) * HID + lane];
    float w3 = W2s[(k + 3) * HID + lane];
    float4 a;
    a = *(const float4*)&z0[k];
    c0 += a.x * w0 + a.y * w1 + a.z * w2 + a.w * w3;
    a = *(const float4*)&z1[k];
    c1 += a.x * w0 + a.y * w1 + a.z * w2 + a.w * w3;
    a = *(const float4*)&z2[k];
    c2 += a.x * w0 + a.y * w1 + a.z * w2 + a.w * w3;
    a = *(const float4*)&z3[k];
    c3 += a.x * w0 + a.y * w1 + a.z * w2 + a.w * w3;
  }
  size_t rb = (size_t)(node0 + wave * 4) * HID + lane;
  hout[rb + 0 * HID] = fmaxf(0.f, c0);
  hout[rb + 1 * HID] = fmaxf(0.f, c1);
  hout[rb + 2 * HID] = fmaxf(0.f, c2);
  hout[rb + 3 * HID] = fmaxf(0.f, c3);
}

// ---------------------------------------------------------------------------
// K8: feature sums over N, output GEMM [8,320]@[320,10]+b, write curv_loss.
// ---------------------------------------------------------------------------
__global__ __launch_bounds__(320) void k_out(
    const float* X, const float* h1, const float* h2, const float* h3,
    const float* out_W, const float* out_b, const float* loss_acc,
    float* out) {
  int b = blockIdx.x;
  int t = threadIdx.x;  // 320
  __shared__ float S[320];
  const float* src;
  int C, col;
  if (t < 128)      { src = X  + (size_t)b * NNODE * DIM; C = DIM; col = t; }
  else if (t < 192) { src = h1 + (size_t)b * NNODE * HID; C = HID; col = t - 128; }
  else if (t < 256) { src = h2 + (size_t)b * NNODE * HID; C = HID; col = t - 192; }
  else              { src = h3 + (size_t)b * NNODE * HID; C = HID; col = t - 256; }
  float s = 0.f;
  for (int n = 0; n < NNODE; n++) s += src[(size_t)n * C + col];
  S[t] = s;
  __syncthreads();
  if (t < 10) {
    float acc = out_b[t];
    for (int d = 0; d < 320; d++) acc += S[d] * out_W[d * 10 + t];
    out[b * 10 + t] = acc;
  }
  if (b == 0 && t == 0) out[80] = *loss_acc;
}

// ---------------------------------------------------------------------------
extern "C" void kernel_launch(void* const* d_in, const int* in_sizes, int n_in,
                              void* d_out, int out_size, void* d_ws,
                              size_t ws_size, hipStream_t stream) {
  const float* X       = (const float*)d_in[0];
  const float* A       = (const float*)d_in[1];
  const int*   p       = (const int*)d_in[2];
  const float* curv_W1 = (const float*)d_in[3];
  const float* curv_b1 = (const float*)d_in[4];
  const float* curv_W2 = (const float*)d_in[5];
  const float* curv_b2 = (const float*)d_in[6];
  const float* wm_W1   = (const float*)d_in[7];
  const float* wm_b1   = (const float*)d_in[8];
  const float* wm_W2   = (const float*)d_in[9];
  const float* wm_b2   = (const float*)d_in[10];
  const float* wm_W3   = (const float*)d_in[11];
  const float* wm_b3   = (const float*)d_in[12];
  const float* fn_W1   = (const float*)d_in[13];
  const float* fn_b1   = (const float*)d_in[14];
  const float* fn_W2   = (const float*)d_in[15];
  const float* fn_b2   = (const float*)d_in[16];
  const float* gin_eps = (const float*)d_in[17];
  const float* g0_W1   = (const float*)d_in[18];
  const float* g0_b1   = (const float*)d_in[19];
  const float* g0_W2   = (const float*)d_in[20];
  const float* g0_b2   = (const float*)d_in[21];
  const float* g1_W1   = (const float*)d_in[22];
  const float* g1_b1   = (const float*)d_in[23];
  const float* g1_W2   = (const float*)d_in[24];
  const float* g1_b2   = (const float*)d_in[25];
  const float* g2_W1   = (const float*)d_in[26];
  const float* g2_b1   = (const float*)d_in[27];
  const float* g2_W2   = (const float*)d_in[28];
  const float* g2_b2   = (const float*)d_in[29];
  const float* out_W   = (const float*)d_in[30];
  const float* out_b   = (const float*)d_in[31];
  float* out = (float*)d_out;

  float* ws = (float*)d_ws;
  size_t o = 0;
  float* loss_acc = ws + o; o += 16;
  float* c1       = ws + o; o += 16;
  float* kap      = ws + o; o += BN;
  float* f        = ws + o; o += (size_t)BN * 3;
  float* deg      = ws + o; o += BN;
  float* M1       = ws + o; o += BN;
  float* M2       = ws + o; o += BN;
  float* GG       = ws + o; o += (size_t)BN * 12;
  float* h1       = ws + o; o += (size_t)BN * HID;
  float* h2       = ws + o; o += (size_t)BN * HID;
  float* h3       = ws + o; o += (size_t)BN * HID;
  int* cnt = (int*)(ws + o); o += BN;
  int* csr = (int*)(ws + o); o += (size_t)BN * CAP;

  k_node_mlps<<<BN / 16 + 1, 256, 0, stream>>>(
      X, curv_W1, curv_b1, curv_W2, curv_b2, fn_W1, fn_b1, fn_W2, fn_b2,
      wm_W1, wm_b1, wm_W2, wm_b2, wm_W3, wm_b3, kap, f, c1);
  k_csr_masks<<<BN / 4 + BATCH, 256, 0, stream>>>(A, kap, p, csr, cnt, deg,
                                                  M1, M2, loss_acc);
  k_pass1_gamma<<<BN / 256, 256, 0, stream>>>(f, csr, cnt, deg, c1, GG);
  k_pass2<<<BN / 256, 256, 0, stream>>>(f, kap, deg, GG, csr, cnt, c1,
                                        loss_acc);
  k_gin<128><<<BN / 16, 256, 0, stream>>>(X, g0_W1, g0_b1, g0_W2, g0_b2,
                                          gin_eps, 0, csr, cnt, nullptr, h1);
  k_gin<64><<<BN / 16, 256, 0, stream>>>(h1, g1_W1, g1_b1, g1_W2, g1_b2,
                                         gin_eps, 1, csr, cnt, M1, h2);
  k_gin<64><<<BN / 16, 256, 0, stream>>>(h2, g2_W1, g2_b1, g2_W2, g2_b2,
                                         gin_eps, 2, csr, cnt, M2, h3);
  k_out<<<BATCH, 320, 0, stream>>>(X, h1, h2, h3, out_W, out_b, loss_acc, out);
}

// Round 3
// 245.244 us; speedup vs baseline: 1.4618x; 1.4618x over previous
//
#include <hip/hip_runtime.h>
#include <math.h>

// Problem constants
#define BATCH 8
#define NNODE 512
#define BN 4096           // BATCH*NNODE
#define DIM 128
#define HID 64
#define CAP 64            // max neighbors per row (mean ~20, 10 sigma margin)

__device__ __forceinline__ float sigmoidf(float x) {
  return 1.f / (1.f + expf(-x));
}
__device__ __forceinline__ float wave_sum(float v) {
  for (int off = 1; off < 64; off <<= 1) v += __shfl_xor(v, off, 64);
  return v;
}

// ---------------------------------------------------------------------------
// K1: per-node MLPs kappa + f0..f2, one MLP per block (grid 4*256+1).
// 16 nodes/block, 4 nodes/wave: each W1 LDS read feeds 4 FMAs.
// Block 1024: c1 = wm_mlp(1.0)  (weights == c1*A since A is binary).
// ---------------------------------------------------------------------------
__global__ __launch_bounds__(256) void k_node_mlps(
    const float* X, const float* cW1, const float* cb1, const float* cW2,
    const float* cb2, const float* fW1, const float* fb1, const float* fW2,
    const float* fb2, const float* wm_W1, const float* wm_b1,
    const float* wm_W2, const float* wm_b2, const float* wm_W3,
    const float* wm_b3, float* kap, float* f, float* c1_out) {
  int bid = blockIdx.x;
  if (bid == 4 * (BN / 16)) {  // scalar weight-MLP(1.0)
    __shared__ float u[64];
    __shared__ float y[32];
    int l = threadIdx.x;
    if (l < 64) u[l] = fmaxf(0.f, wm_W1[l] + wm_b1[l]);
    __syncthreads();
    if (l < 32) {
      float a = wm_b2[l];
      for (int k = 0; k < 64; k++) a += u[k] * wm_W2[k * 32 + l];
      y[l] = fmaxf(0.f, a);
    }
    __syncthreads();
    if (l == 0) {
      float a = wm_b3[0];
      for (int k = 0; k < 32; k++) a += y[k] * wm_W3[k];
      *c1_out = sigmoidf(a);
    }
    return;
  }
  int m = bid >> 8;           // 0..3: which MLP
  int grp = bid & 255;        // node group
  __shared__ float W1s[DIM * HID];  // 32KB
  __shared__ float xs[16][DIM];     // 8KB
  int tid = threadIdx.x, wave = tid >> 6, lane = tid & 63;
  int node0 = grp * 16;
  const float* W1 = (m == 0) ? cW1 : fW1 + (size_t)(m - 1) * DIM * HID;
  for (int t = tid; t < 16 * DIM / 4; t += 256)
    ((float4*)xs)[t] = ((const float4*)(X + (size_t)node0 * DIM))[t];
  for (int t = tid; t < DIM * HID / 4; t += 256)
    ((float4*)W1s)[t] = ((const float4*)W1)[t];
  __syncthreads();
  const float* b1 = (m == 0) ? cb1 : fb1 + (m - 1) * HID;
  const float* W2 = (m == 0) ? cW2 : fW2 + (m - 1) * HID;
  float b2v = (m == 0) ? cb2[0] : fb2[m - 1];
  const float* x0 = xs[wave * 4 + 0];
  const float* x1 = xs[wave * 4 + 1];
  const float* x2 = xs[wave * 4 + 2];
  const float* x3 = xs[wave * 4 + 3];
  float w2l = W2[lane];
  float bb = b1[lane];
  float acc0 = bb, acc1 = bb, acc2 = bb, acc3 = bb;
  for (int k = 0; k < DIM; k += 4) {
    float w0 = W1s[(k + 0) * HID + lane];
    float w1 = W1s[(k + 1) * HID + lane];
    float w2 = W1s[(k + 2) * HID + lane];
    float w3 = W1s[(k + 3) * HID + lane];
    float4 a;
    a = *(const float4*)&x0[k];
    acc0 += a.x * w0 + a.y * w1 + a.z * w2 + a.w * w3;
    a = *(const float4*)&x1[k];
    acc1 += a.x * w0 + a.y * w1 + a.z * w2 + a.w * w3;
    a = *(const float4*)&x2[k];
    acc2 += a.x * w0 + a.y * w1 + a.z * w2 + a.w * w3;
    a = *(const float4*)&x3[k];
    acc3 += a.x * w0 + a.y * w1 + a.z * w2 + a.w * w3;
  }
  float s0 = wave_sum(fmaxf(0.f, acc0) * w2l);
  float s1 = wave_sum(fmaxf(0.f, acc1) * w2l);
  float s2 = wave_sum(fmaxf(0.f, acc2) * w2l);
  float s3 = wave_sum(fmaxf(0.f, acc3) * w2l);
  if (lane < 4) {
    float sv = (lane == 0) ? s0 : (lane == 1) ? s1 : (lane == 2) ? s2 : s3;
    float s = sigmoidf(sv + b2v);
    int node = node0 + wave * 4 + lane;
    if (m == 0) kap[node] = s;
    else f[node * 3 + (m - 1)] = s;
  }
}

// ---------------------------------------------------------------------------
// K2: fused CSR build (blocks [0,1024): 4 rows/block, wave/row, tail padded
// with 0) + top-k rank masks (blocks [1024,1032)) + loss_acc zero.
// ---------------------------------------------------------------------------
__global__ __launch_bounds__(256) void k_csr_masks(
    const float* A, const float* kap, const int* p_ptr, int* csr, int* cnt_arr,
    float* deg, float* M1, float* M2, float* loss_acc) {
  int bid = blockIdx.x;
  if (bid < BN / 4) {
    int wave = threadIdx.x >> 6, lane = threadIdx.x & 63;
    int r = bid * 4 + wave;
    const float* row = A + (size_t)r * NNODE;
    int base = r * CAP, cnt = 0;
    for (int c = 0; c < NNODE / 64; c++) {
      int j = c * 64 + lane;
      bool nz = (row[j] != 0.f);
      unsigned long long mb = __ballot(nz);
      if (nz) {
        int pos = __popcll(mb & ((1ull << lane) - 1ull));
        int slot = cnt + pos;
        if (slot < CAP) csr[base + slot] = j;
      }
      cnt += (int)__popcll(mb);
    }
    int cc = cnt < CAP ? cnt : CAP;
    if (lane >= cc) csr[base + lane] = 0;  // pad tail (safe: disjoint slots)
    if (lane == 0) {
      cnt_arr[r] = cc;
      deg[r] = (float)cnt;
    }
    return;
  }
  int b = bid - BN / 4;
  if (threadIdx.x == 0 && b == 0) *loss_acc = 0.f;
  __shared__ float ks[NNODE];
  for (int t = threadIdx.x; t < NNODE; t += 256) ks[t] = kap[b * NNODE + t];
  __syncthreads();
  int p = *p_ptr;
  int num1 = (NNODE * p) / 100;
  int num2 = (NNODE * 2 * p) / 100;
  int numm = num1 > num2 ? num1 : num2;
  for (int i = threadIdx.x; i < NNODE; i += 256) {
    float v = ks[i];
    int rank = 0;
    for (int j = 0; j < NNODE; j++) {
      float u = ks[j];
      rank += (u > v) || (u == v && j < i);  // jax.lax.top_k tie-break
    }
    M1[b * NNODE + i] = (rank < num1) ? 0.f : 1.f;
    M2[b * NNODE + i] = (rank < numm) ? 0.f : 1.f;
  }
}

// ---------------------------------------------------------------------------
// K3: build mask-filtered CSRs for GIN layers 1,2 (row-mask folds to cnt=0,
// tails padded with 0).  4 rows/block, wave/row.
// ---------------------------------------------------------------------------
__global__ __launch_bounds__(256) void k_filter(
    const int* csr, const int* cnt, const float* M1, const float* M2,
    int* csr1, int* cnt1, int* csr2, int* cnt2) {
  int wave = threadIdx.x >> 6, lane = threadIdx.x & 63;
  int r = blockIdx.x * 4 + wave;
  int b9 = r & ~(NNODE - 1);
  int n = cnt[r];
  int j = csr[r * CAP + lane];
  bool have = lane < n;
  {
    bool v = have && (M1[r] != 0.f) && (M1[b9 + j] != 0.f);
    unsigned long long mb = __ballot(v);
    int pos = __popcll(mb & ((1ull << lane) - 1ull));
    int c = __popcll(mb);
    if (v) csr1[r * CAP + pos] = j;
    if (lane >= c) csr1[r * CAP + lane] = 0;
    if (lane == 0) cnt1[r] = c;
  }
  {
    bool v = have && (M2[r] != 0.f) && (M2[b9 + j] != 0.f);
    unsigned long long mb = __ballot(v);
    int pos = __popcll(mb & ((1ull << lane) - 1ull));
    int c = __popcll(mb);
    if (v) csr2[r * CAP + pos] = j;
    if (lane >= c) csr2[r * CAP + lane] = 0;
    if (lane == 0) cnt2[r] = c;
  }
}

// ---------------------------------------------------------------------------
// K4: curvature pass1 + gamma terms, wave per row (lane = neighbor).
// GG[r*12]: [gamma_i, df_i, fi*df_i] i=0..2, then s1_i.
// ---------------------------------------------------------------------------
__global__ __launch_bounds__(256) void k_pass1_gamma(
    const float* f, const int* csr, const int* cnt, const float* deg,
    const float* c1p, float* GG) {
  int wave = threadIdx.x >> 6, lane = threadIdx.x & 63;
  int r = blockIdx.x * 4 + wave;
  int b9 = r & ~(NNODE - 1);
  int n = cnt[r];
  int j = csr[r * CAP + lane];
  float f0 = 0.f, f1 = 0.f, f2 = 0.f;
  if (lane < n) {
    const float* fj = f + (size_t)(b9 + j) * 3;
    f0 = fj[0]; f1 = fj[1]; f2 = fj[2];
  }
  float s10 = wave_sum(f0), s11 = wave_sum(f1), s12 = wave_sum(f2);
  float s20 = wave_sum(f0 * f0), s21 = wave_sum(f1 * f1),
        s22 = wave_sum(f2 * f2);
  if (lane < 3) {
    float s1 = (lane == 0) ? s10 : (lane == 1) ? s11 : s12;
    float s2 = (lane == 0) ? s20 : (lane == 1) ? s21 : s22;
    float c1 = *c1p, dA = deg[r];
    float fi = f[r * 3 + lane];
    float gamma = 0.5f * c1 * (fi * fi * dA - 2.f * fi * s1 + s2);
    float df = c1 * (fi * dA - s1);
    float* o = GG + (size_t)r * 12;
    o[lane * 3 + 0] = gamma;
    o[lane * 3 + 1] = df;
    o[lane * 3 + 2] = fi * df;
    o[9 + lane] = s1;
  }
}

// ---------------------------------------------------------------------------
// K5: curvature pass2 + loss, wave per row; block-reduced single atomic.
// ---------------------------------------------------------------------------
__global__ __launch_bounds__(256) void k_pass2(
    const float* f, const float* kap, const float* deg, const float* GG,
    const int* csr, const int* cnt, const float* c1p, float* loss_acc) {
  __shared__ float part[4];
  int wave = threadIdx.x >> 6, lane = threadIdx.x & 63;
  int r = blockIdx.x * 4 + wave;
  int b9 = r & ~(NNODE - 1);
  int n = cnt[r];
  int j = csr[r * CAP + lane];
  float T[9];
  for (int c = 0; c < 9; c++) T[c] = 0.f;
  if (lane < n) {
    const float4* g = (const float4*)(GG + (size_t)(b9 + j) * 12);
    float4 g0 = g[0], g1 = g[1], g2 = g[2];
    T[0] = g0.x; T[1] = g0.y; T[2] = g0.z;
    T[3] = g0.w; T[4] = g1.x; T[5] = g1.y;
    T[6] = g1.z; T[7] = g1.w; T[8] = g2.x;
  }
  for (int c = 0; c < 9; c++) T[c] = wave_sum(T[c]);
  float kp = kap[r];
  float local = 0.f;
  if (lane < 3) {
    int i = lane;
    float c1 = *c1p, dA = deg[r];
    const float* o = GG + (size_t)r * 12;
    float fi = f[r * 3 + i];
    float s1 = o[9 + i];
    float gamma = o[i * 3 + 0], df = o[i * 3 + 1];
    float dgamma = c1 * (gamma * dA - T[i * 3 + 0]);
    float gfd = 0.5f * c1 * (fi * df * dA - fi * T[i * 3 + 1] - df * s1 +
                             T[i * 3 + 2]);
    float gamma2 = 0.5f * dgamma - gfd;
    local = fmaxf(0.f, kp * gamma - gamma2);
  }
  if (lane == 0) local -= 3.f * kp;  // "- kappa.sum()" once per f_i
  local = wave_sum(local);
  if (lane == 0) part[wave] = local;
  __syncthreads();
  if (threadIdx.x == 0)
    atomicAdd(loss_acc, part[0] + part[1] + part[2] + part[3]);
}

// ---------------------------------------------------------------------------
// GIN layer: agg = (1+eps)*h + sum_{j in filtered nbr} h[j];
// h' = relu(relu(agg@W1+b1)@W2+b2).  8 nodes/block (2/wave), grid 512.
// Gather: branchless, int4 index chunks, 4 independent row loads in flight.
// ---------------------------------------------------------------------------
template <int CIN>
__global__ __launch_bounds__(256) void k_gin(
    const float* hin, const float* W1, const float* b1, const float* W2,
    const float* b2, const float* eps_arr, int eps_idx, const int* csr,
    const int* cnt, float* hout) {
  __shared__ float W1s[CIN * HID];
  __shared__ float W2s[HID * HID];
  __shared__ float aggs[8][CIN];
  __shared__ float zs[8][HID];
  int tid = threadIdx.x, wave = tid >> 6, lane = tid & 63;
  int node0 = blockIdx.x * 8;
  for (int t = tid; t < CIN * HID / 4; t += 256)
    ((float4*)W1s)[t] = ((const float4*)W1)[t];
  for (int t = tid; t < HID * HID / 4; t += 256)
    ((float4*)W2s)[t] = ((const float4*)W2)[t];
  float eps1 = 1.f + eps_arr[eps_idx];
  for (int i = 0; i < 2; i++) {
    int ln = wave * 2 + i;
    int r = node0 + ln;
    int b9 = r & ~(NNODE - 1);
    const float* hi = hin + (size_t)r * CIN;
    float a0 = eps1 * hi[lane];
    float a1 = (CIN == 128) ? eps1 * hi[lane + 64] : 0.f;
    int n = cnt[r];
    const int* nb = csr + r * CAP;
    for (int t = 0; t < n; t += 4) {
      int4 j4 = *(const int4*)&nb[t];
      const float* p0 = hin + (size_t)(b9 + j4.x) * CIN;
      const float* p1 = hin + (size_t)(b9 + j4.y) * CIN;
      const float* p2 = hin + (size_t)(b9 + j4.z) * CIN;
      const float* p3 = hin + (size_t)(b9 + j4.w) * CIN;
      float m1 = (t + 1 < n) ? 1.f : 0.f;
      float m2 = (t + 2 < n) ? 1.f : 0.f;
      float m3 = (t + 3 < n) ? 1.f : 0.f;
      a0 += p0[lane] + m1 * p1[lane] + m2 * p2[lane] + m3 * p3[lane];
      if (CIN == 128)
        a1 += p0[lane + 64] + m1 * p1[lane + 64] + m2 * p2[lane + 64] +
              m3 * p3[lane + 64];
    }
    aggs[ln][lane] = a0;
    if (CIN == 128) aggs[ln][lane + 64] = a1;
  }
  __syncthreads();
  const float* x0 = aggs[wave * 2 + 0];
  const float* x1 = aggs[wave * 2 + 1];
  float bb = b1[lane];
  float acc0 = bb, acc1 = bb;
  for (int k = 0; k < CIN; k += 4) {
    float w0 = W1s[(k + 0) * HID + lane];
    float w1 = W1s[(k + 1) * HID + lane];
    float w2 = W1s[(k + 2) * HID + lane];
    float w3 = W1s[(k + 3) * HID + lane];
    float4 a;
    a = *(const float4*)&x0[k];
    acc0 += a.x * w0 + a.y * w1 + a.z * w2 + a.w * w3;
    a = *(const float4*)&x1[k];
    acc1 += a.x * w0 + a.y * w1 + a.z * w2 + a.w * w3;
  }
  zs[wave * 2 + 0][lane] = fmaxf(0.f, acc0);
  zs[wave * 2 + 1][lane] = fmaxf(0.f, acc1);
  const float* z0 = zs[wave * 2 + 0];
  const float* z1 = zs[wave * 2 + 1];
  float b2b = b2[lane];
  float c0 = b2b, c1 = b2b;
  for (int k = 0; k < HID; k += 4) {
    float w0 = W2s[(k + 0) * HID + lane];
    float w1 = W2s[(k + 1) * HID + lane];
    float w2 = W2s[(k + 2) * HID + lane];
    float w3 = W2s[(k + 3) * HID + lane];
    float4 a;
    a = *(const float4*)&z0[k];
    c0 += a.x * w0 + a.y * w1 + a.z * w2 + a.w * w3;
    a = *(const float4*)&z1[k];
    c1 += a.x * w0 + a.y * w1 + a.z * w2 + a.w * w3;
  }
  size_t rb = (size_t)(node0 + wave * 2) * HID + lane;
  hout[rb + 0 * HID] = fmaxf(0.f, c0);
  hout[rb + 1 * HID] = fmaxf(0.f, c1);
}

// ---------------------------------------------------------------------------
// K9: feature sums over N (2-way row split), output GEMM [8,320]@[320,10]+b.
// ---------------------------------------------------------------------------
__global__ __launch_bounds__(640) void k_out(
    const float* X, const float* h1, const float* h2, const float* h3,
    const float* out_W, const float* out_b, const float* loss_acc,
    float* out) {
  int b = blockIdx.x;
  int t = threadIdx.x;  // 640
  __shared__ float S[640];
  int half = t / 320, c = t % 320;
  const float* src;
  int C, col;
  if (c < 128)      { src = X  + (size_t)b * NNODE * DIM; C = DIM; col = c; }
  else if (c < 192) { src = h1 + (size_t)b * NNODE * HID; C = HID; col = c - 128; }
  else if (c < 256) { src = h2 + (size_t)b * NNODE * HID; C = HID; col = c - 192; }
  else              { src = h3 + (size_t)b * NNODE * HID; C = HID; col = c - 256; }
  int n0 = half * (NNODE / 2);
  float s = 0.f;
  for (int n = n0; n < n0 + NNODE / 2; n++) s += src[(size_t)n * C + col];
  S[t] = s;
  __syncthreads();
  if (t < 10) {
    float acc = out_b[t];
    for (int d = 0; d < 320; d++)
      acc += (S[d] + S[d + 320]) * out_W[d * 10 + t];
    out[b * 10 + t] = acc;
  }
  if (b == 0 && t == 0) out[80] = *loss_acc;
}

// ---------------------------------------------------------------------------
extern "C" void kernel_launch(void* const* d_in, const int* in_sizes, int n_in,
                              void* d_out, int out_size, void* d_ws,
                              size_t ws_size, hipStream_t stream) {
  const float* X       = (const float*)d_in[0];
  const float* A       = (const float*)d_in[1];
  const int*   p       = (const int*)d_in[2];
  const float* curv_W1 = (const float*)d_in[3];
  const float* curv_b1 = (const float*)d_in[4];
  const float* curv_W2 = (const float*)d_in[5];
  const float* curv_b2 = (const float*)d_in[6];
  const float* wm_W1   = (const float*)d_in[7];
  const float* wm_b1   = (const float*)d_in[8];
  const float* wm_W2   = (const float*)d_in[9];
  const float* wm_b2   = (const float*)d_in[10];
  const float* wm_W3   = (const float*)d_in[11];
  const float* wm_b3   = (const float*)d_in[12];
  const float* fn_W1   = (const float*)d_in[13];
  const float* fn_b1   = (const float*)d_in[14];
  const float* fn_W2   = (const float*)d_in[15];
  const float* fn_b2   = (const float*)d_in[16];
  const float* gin_eps = (const float*)d_in[17];
  const float* g0_W1   = (const float*)d_in[18];
  const float* g0_b1   = (const float*)d_in[19];
  const float* g0_W2   = (const float*)d_in[20];
  const float* g0_b2   = (const float*)d_in[21];
  const float* g1_W1   = (const float*)d_in[22];
  const float* g1_b1   = (const float*)d_in[23];
  const float* g1_W2   = (const float*)d_in[24];
  const float* g1_b2   = (const float*)d_in[25];
  const float* g2_W1   = (const float*)d_in[26];
  const float* g2_b1   = (const float*)d_in[27];
  const float* g2_W2   = (const float*)d_in[28];
  const float* g2_b2   = (const float*)d_in[29];
  const float* out_W   = (const float*)d_in[30];
  const float* out_b   = (const float*)d_in[31];
  float* out = (float*)d_out;

  float* ws = (float*)d_ws;
  size_t o = 0;
  float* loss_acc = ws + o; o += 16;
  float* c1       = ws + o; o += 16;
  float* kap      = ws + o; o += BN;
  float* f        = ws + o; o += (size_t)BN * 3 + 16;
  float* deg      = ws + o; o += BN;
  float* M1       = ws + o; o += BN;
  float* M2       = ws + o; o += BN;
  float* GG       = ws + o; o += (size_t)BN * 12;
  float* h1       = ws + o; o += (size_t)BN * HID;
  float* h2       = ws + o; o += (size_t)BN * HID;
  float* h3       = ws + o; o += (size_t)BN * HID;
  int* cnt  = (int*)(ws + o); o += BN;
  int* cnt1 = (int*)(ws + o); o += BN;
  int* cnt2 = (int*)(ws + o); o += BN;
  int* csr  = (int*)(ws + o); o += (size_t)BN * CAP;
  int* csr1 = (int*)(ws + o); o += (size_t)BN * CAP;
  int* csr2 = (int*)(ws + o); o += (size_t)BN * CAP;

  k_node_mlps<<<4 * (BN / 16) + 1, 256, 0, stream>>>(
      X, curv_W1, curv_b1, curv_W2, curv_b2, fn_W1, fn_b1, fn_W2, fn_b2,
      wm_W1, wm_b1, wm_W2, wm_b2, wm_W3, wm_b3, kap, f, c1);
  k_csr_masks<<<BN / 4 + BATCH, 256, 0, stream>>>(A, kap, p, csr, cnt, deg,
                                                  M1, M2, loss_acc);
  k_filter<<<BN / 4, 256, 0, stream>>>(csr, cnt, M1, M2, csr1, cnt1, csr2,
                                       cnt2);
  k_pass1_gamma<<<BN / 4, 256, 0, stream>>>(f, csr, cnt, deg, c1, GG);
  k_pass2<<<BN / 4, 256, 0, stream>>>(f, kap, deg, GG, csr, cnt, c1, loss_acc);
  k_gin<128><<<BN / 8, 256, 0, stream>>>(X, g0_W1, g0_b1, g0_W2, g0_b2,
                                         gin_eps, 0, csr, cnt, h1);
  k_gin<64><<<BN / 8, 256, 0, stream>>>(h1, g1_W1, g1_b1, g1_W2, g1_b2,
                                        gin_eps, 1, csr1, cnt1, h2);
  k_gin<64><<<BN / 8, 256, 0, stream>>>(h2, g2_W1, g2_b1, g2_W2, g2_b2,
                                        gin_eps, 2, csr2, cnt2, h3);
  k_out<<<BATCH, 640, 0, stream>>>(X, h1, h2, h3, out_W, out_b, loss_acc, out);
}